// Round 23
// baseline (139.765 us; speedup 1.0000x reference)
//
#include <hip/hip_runtime.h>
#include <stdint.h>

#define NH 12
#define DH 64
#define HW_ 32
#define SEQ 1024
#define CDIM 768
#define BATCH 8
#define BHN (BATCH*NH)

#define LOG2E 1.44269504f
#define KSCALE 0.18033688f   // 0.125 * log2(e), folded into K

typedef unsigned short u16;
typedef __attribute__((ext_vector_type(4))) float f32x4;
typedef __attribute__((ext_vector_type(8))) short bf16x8;

static __device__ __forceinline__ u16 f2bf(float f) {
  union { float f; unsigned u; } v; v.f = f;
  unsigned r = v.u + 0x7fff + ((v.u >> 16) & 1);
  return (u16)(r >> 16);
}
// pack hi16(round-half-up(b)) : hi16(round-half-up(a))  (a -> low half)
static __device__ __forceinline__ unsigned pk_bf2(float a, float b) {
  union { float f; unsigned u; } ua, ub; ua.f = a; ub.f = b;
  return __builtin_amdgcn_perm(ub.u + 0x8000u, ua.u + 0x8000u, 0x07060302u);
}

#define GLDS(gp, lp) __builtin_amdgcn_global_load_lds( \
  (const __attribute__((address_space(1))) unsigned int*)(gp), \
  (__attribute__((address_space(3))) unsigned int*)(lp), 16, 0, 0)

// ---------------- fused prep: x->bf16 (blocks 0..6143), w_qkv^T (next 432), w_out^T (last 144) ----------------
__device__ __forceinline__ void transcvt_body(const float* __restrict__ w, u16* __restrict__ wt,
                                              int R, int C, int bx, int by, int tid) {
  __shared__ float t[64][65];
  const int tx = tid & 63, ty = tid >> 6;
  int c0 = bx * 64, r0 = by * 64;
  #pragma unroll
  for (int i = 0; i < 16; ++i) {
    int r = ty + i * 4;
    t[r][tx] = w[(size_t)(r0 + r) * C + c0 + tx];
  }
  __syncthreads();
  #pragma unroll
  for (int i = 0; i < 16; ++i) {
    int c = ty + i * 4;
    wt[(size_t)(c0 + c) * R + r0 + tx] = f2bf(t[tx][c]);
  }
}

__global__ void k_prep(const float* __restrict__ x, u16* __restrict__ xb,
                       const float* __restrict__ wqkv, u16* __restrict__ wqkvt,
                       const float* __restrict__ wout, u16* __restrict__ woutt) {
  const int bid = blockIdx.x, tid = threadIdx.x;
  if (bid < 6144) {
    int i = bid * 256 + tid;
    const float4 v = *(const float4*)(x + (size_t)i * 4);
    uint2 o;
    o.x = (unsigned)f2bf(v.x) | ((unsigned)f2bf(v.y) << 16);
    o.y = (unsigned)f2bf(v.z) | ((unsigned)f2bf(v.w) << 16);
    *(uint2*)(xb + (size_t)i * 4) = o;
  } else if (bid < 6144 + 432) {
    int b = bid - 6144;
    transcvt_body(wqkv, wqkvt, 768, 2304, b % 36, b / 36, tid);
  } else {
    int b = bid - 6144 - 432;
    transcvt_body(wout, woutt, 768, 768, b % 12, b / 12, tid);
  }
}

// ---------------- GEMM (QKV): A(8192,768)bf16 x Bt(2304,768)bf16, 128x128 tile, 8 waves ----------------
// TRIPLE-buffered LDS, 2-tile-ahead prefetch, counted vmcnt BEFORE the raw barrier.
// Q (bh,p,d); K scaled by KSCALE (bh,p,d); V TRANSPOSED to (bh,d,p).
template<int NT>
__global__ __launch_bounds__(512, 8) void k_gemm(
    const u16* __restrict__ A, const u16* __restrict__ Bt,
    const float* __restrict__ bias,
    void* __restrict__ o0, void* __restrict__ o1, void* __restrict__ o2,
    int nwg) {
  __shared__ u16 As[3][128][32];   // 24 KB
  __shared__ u16 Bs[3][128][32];   // 24 KB
  const int cpx = nwg >> 3;                       // nwg % 8 == 0
  const int swz = (blockIdx.x & 7) * cpx + (blockIdx.x >> 3);
  const int tid = threadIdx.x, w = tid >> 6, l = tid & 63;
  const int wr = w >> 1, wc = w & 1;              // wave tile 32x64
  const int rr = l & 15, g4 = l >> 4;
  const int m0 = (swz / NT) * 128, n0 = (swz % NT) * 128;
  const int K = CDIM;
  const int NT_K = K / 32;                        // 24 K-steps
  f32x4 acc[2][4] = {};

  auto stage = [&](int buf, int t) {
    int k0 = t * 32;
    int c = tid;                                   // 512 chunks of 16B each for A and B
    int row = c >> 2, kc = (c & 3) * 8;
    GLDS(A + (size_t)(m0 + row) * K + k0 + kc, ((u16*)As) + buf * 4096 + c * 8);
    GLDS(Bt + (size_t)(n0 + row) * K + k0 + kc, ((u16*)Bs) + buf * 4096 + c * 8);
  };
  stage(0, 0);
  stage(1, 1);
  asm volatile("s_waitcnt vmcnt(2)" ::: "memory");   // tile 0 (own ops) complete
  __builtin_amdgcn_s_barrier();                       // -> tile 0 complete for ALL waves
  for (int t = 0; t < NT_K; ++t) {
    const int cur = t % 3;
    if (t + 2 < NT_K) stage((t + 2) % 3, t + 2);
    bf16x8 af[2], bfr[4];
    #pragma unroll
    for (int mm = 0; mm < 2; ++mm)
      af[mm] = *(const bf16x8*)(((const u16*)As) + cur * 4096 + (wr * 32 + mm * 16 + rr) * 32 + g4 * 8);
    #pragma unroll
    for (int nn = 0; nn < 4; ++nn)
      bfr[nn] = *(const bf16x8*)(((const u16*)Bs) + cur * 4096 + (wc * 64 + nn * 16 + rr) * 32 + g4 * 8);
    __builtin_amdgcn_s_setprio(1);
    #pragma unroll
    for (int mm = 0; mm < 2; ++mm)
      #pragma unroll
      for (int nn = 0; nn < 4; ++nn)
        acc[mm][nn] = __builtin_amdgcn_mfma_f32_16x16x32_bf16(af[mm], bfr[nn], acc[mm][nn], 0, 0, 0);
    __builtin_amdgcn_s_setprio(0);
    if (t + 2 < NT_K) asm volatile("s_waitcnt vmcnt(2)" ::: "memory");
    else              asm volatile("s_waitcnt vmcnt(0)" ::: "memory");
    __builtin_amdgcn_s_barrier();
  }
  #pragma unroll
  for (int mm = 0; mm < 2; ++mm)
    #pragma unroll
    for (int nn = 0; nn < 4; ++nn) {
      int row0 = m0 + wr * 32 + mm * 16 + g4 * 4;
      int col = n0 + wc * 64 + nn * 16 + rr;
      float bb = bias[col];
      int which = col / CDIM, rem = col % CDIM;
      int hh = rem >> 6, d = rem & 63;
      int b = row0 >> 10, p = row0 & 1023;
      if (which == 2) {
        uint2 pk;
        pk.x = (unsigned)f2bf(acc[mm][nn][0] + bb) | ((unsigned)f2bf(acc[mm][nn][1] + bb) << 16);
        pk.y = (unsigned)f2bf(acc[mm][nn][2] + bb) | ((unsigned)f2bf(acc[mm][nn][3] + bb) << 16);
        *(uint2*)&((u16*)o2)[((size_t)(b * NH + hh) * DH + d) * SEQ + p] = pk;
      } else if (which == 1) {
        #pragma unroll
        for (int j = 0; j < 4; ++j)
          ((u16*)o1)[(((size_t)(b * NH + hh)) * SEQ + p + j) * DH + d] = f2bf((acc[mm][nn][j] + bb) * KSCALE);
      } else {
        #pragma unroll
        for (int j = 0; j < 4; ++j)
          ((u16*)o0)[(((size_t)(b * NH + hh)) * SEQ + p + j) * DH + d] = f2bf(acc[mm][nn][j] + bb);
      }
    }
}

// ---------------- out-proj GEMM: 128x192 tile, 8 waves (4M x 2N), EXACTLY 256 blocks = 1/CU ----------------
// Triple-buffered, 2-ahead prefetch, per-wave counted vmcnt (waves 0-3 stage 3 ops, 4-7 stage 2).
template<int NT>
__global__ __launch_bounds__(512) void k_gemmB(
    const u16* __restrict__ A, const u16* __restrict__ Bt,
    const float* __restrict__ bias, float* __restrict__ out, int nwg) {
  __shared__ u16 As[3][128][32];   // 24 KB
  __shared__ u16 Bs[3][192][32];   // 36 KB
  const int cpx = nwg >> 3;
  const int swz = (blockIdx.x & 7) * cpx + (blockIdx.x >> 3);
  const int tid = threadIdx.x, w = tid >> 6, l = tid & 63;
  const int wr = w >> 1, wc = w & 1;              // wave tile 32x96
  const int rr = l & 15, g4 = l >> 4;
  const int m0 = (swz / NT) * 128, n0 = (swz % NT) * 192;
  const int K = CDIM;
  const int NT_K = K / 32;                        // 24 K-steps
  f32x4 acc[2][6] = {};

  auto stage = [&](int buf, int t) {
    int k0 = t * 32;
    {
      int c = tid;                                 // A: 512 chunks (rows 0..127)
      int row = c >> 2, kc = (c & 3) * 8;
      GLDS(A + (size_t)(m0 + row) * K + k0 + kc, ((u16*)As) + buf * 4096 + c * 8);
    }
    {
      int c = tid;                                 // B: chunks 0..511 (rows 0..127)
      int row = c >> 2, kc = (c & 3) * 8;
      GLDS(Bt + (size_t)(n0 + row) * K + k0 + kc, ((u16*)Bs) + buf * 6144 + c * 8);
    }
    if (tid < 256) {                               // B: chunks 512..767 (rows 128..191)
      int c = 512 + tid;
      int row = c >> 2, kc = (c & 3) * 8;
      GLDS(Bt + (size_t)(n0 + row) * K + k0 + kc, ((u16*)Bs) + buf * 6144 + c * 8);
    }
  };
  stage(0, 0);
  stage(1, 1);
  if (tid < 256) asm volatile("s_waitcnt vmcnt(3)" ::: "memory");  // own tile-0 (3 ops) done
  else           asm volatile("s_waitcnt vmcnt(2)" ::: "memory");  // own tile-0 (2 ops) done
  __builtin_amdgcn_s_barrier();
  for (int t = 0; t < NT_K; ++t) {
    const int cur = t % 3;
    if (t + 2 < NT_K) stage((t + 2) % 3, t + 2);
    bf16x8 af[2], bfr[6];
    #pragma unroll
    for (int mm = 0; mm < 2; ++mm)
      af[mm] = *(const bf16x8*)(((const u16*)As) + cur * 4096 + (wr * 32 + mm * 16 + rr) * 32 + g4 * 8);
    #pragma unroll
    for (int nn = 0; nn < 6; ++nn)
      bfr[nn] = *(const bf16x8*)(((const u16*)Bs) + cur * 6144 + (wc * 96 + nn * 16 + rr) * 32 + g4 * 8);
    __builtin_amdgcn_s_setprio(1);
    #pragma unroll
    for (int mm = 0; mm < 2; ++mm)
      #pragma unroll
      for (int nn = 0; nn < 6; ++nn)
        acc[mm][nn] = __builtin_amdgcn_mfma_f32_16x16x32_bf16(af[mm], bfr[nn], acc[mm][nn], 0, 0, 0);
    __builtin_amdgcn_s_setprio(0);
    if (t + 2 < NT_K) {
      if (tid < 256) asm volatile("s_waitcnt vmcnt(3)" ::: "memory");
      else           asm volatile("s_waitcnt vmcnt(2)" ::: "memory");
    } else {
      asm volatile("s_waitcnt vmcnt(0)" ::: "memory");
    }
    __builtin_amdgcn_s_barrier();
  }
  #pragma unroll
  for (int mm = 0; mm < 2; ++mm)
    #pragma unroll
    for (int nn = 0; nn < 6; ++nn) {
      int row0 = m0 + wr * 32 + mm * 16 + g4 * 4;
      int col = n0 + wc * 96 + nn * 16 + rr;
      float bb = bias[col];
      #pragma unroll
      for (int j = 0; j < 4; ++j)
        out[(size_t)(row0 + j) * CDIM + col] = acc[mm][nn][j] + bb;
    }
}

// ---------------- flash attention with IN-BLOCK rel-pos bias (relbias fused) ----------------
// 8 waves x 16 q-rows; K pre-scaled by 0.125*log2e; bias computed here, pre-scaled by log2e.
// Bias pre-folded into QK MFMA C-init; bh shuffle software-pipelined one tile ahead.
// TRIPLE-buffered K/V (depth-2 prefetch) + counted vmcnt BEFORE raw barrier (R19 pattern).
// P = 2^(sc) via v_exp_f32. No-max softmax (scores bounded). XCD-local K/V.
__global__ __launch_bounds__(512, 4) void k_attn(
    const u16* __restrict__ Q, const u16* __restrict__ Kg,
    const u16* __restrict__ Vtg,
    const float* __restrict__ rph, const float* __restrict__ rpw,
    u16* __restrict__ O) {
  __shared__ u16 Ks[3][64][64];   // 24 KB; [key][d]; swizzle mask (row>>2)&7
  __shared__ u16 Vs[3][64][64];   // 24 KB; [d][key]; swizzle mask row&7
  __shared__ u16 Ps[8][16][72];   // per-wave P tile [query][key]
  const int bid = blockIdx.x;
  const int bhi = bid % 96;            // 96%8==0 -> all q-blocks of a bh on one XCD
  const int q0 = (bid / 96) * 128;
  const int tid = threadIdx.x, w = tid >> 6, l = tid & 63;
  const int rr = l & 15, g4 = l >> 4;
  const u16* Qb = Q + (size_t)bhi * SEQ * DH;
  const u16* Kb = Kg + (size_t)bhi * SEQ * DH;
  const u16* Vb = Vtg + (size_t)bhi * SEQ * DH;   // (64,1024)

  // Q fragment: wave's 16 rows (q0 + w*16 + rr)
  bf16x8 qf[2];
  #pragma unroll
  for (int kk = 0; kk < 2; ++kk)
    qf[kk] = *(const bf16x8*)&Qb[(size_t)(q0 + w * 16 + rr) * DH + kk * 32 + g4 * 8];

  // ---- in-block bias: bH (4 MFMAs, lands directly in bh0/bh1 layout) ----
  const int hq = (q0 >> 5) + (w >> 1);
  float bh0[4], bh1[4];
  {
    f32x4 accH[2] = {{}, {}};
    #pragma unroll
    for (int nn = 0; nn < 2; ++nn) {
      bf16x8 bfr[2];
      #pragma unroll
      for (int kk = 0; kk < 2; ++kk) {
        const float* src = &rph[(size_t)(hq - (nn * 16 + rr) + 31) * DH + kk * 32 + g4 * 8];
        #pragma unroll
        for (int e = 0; e < 8; ++e) bfr[kk][e] = (short)f2bf(src[e]);
      }
      #pragma unroll
      for (int kk = 0; kk < 2; ++kk)
        accH[nn] = __builtin_amdgcn_mfma_f32_16x16x32_bf16(qf[kk], bfr[kk], accH[nn], 0, 0, 0);
    }
    #pragma unroll
    for (int j = 0; j < 4; ++j) { bh0[j] = accH[0][j] * LOG2E; bh1[j] = accH[1][j] * LOG2E; }
  }

  // ---- in-block bias: G = Q . rpw^T (16x64 per wave) into Ks/Vs LDS area, then gather bW ----
  float* Gf = (float*)&Ks[0][0][0];   // 8 waves x 16 x 64 floats = 32 KB (fits in Ks+Vs region)
  #pragma unroll
  for (int nn = 0; nn < 4; ++nn) {
    int j_ = nn * 16 + rr; if (j_ > 62) j_ = 62;
    bf16x8 bfr[2];
    #pragma unroll
    for (int kk = 0; kk < 2; ++kk) {
      const float* src = &rpw[(size_t)j_ * DH + kk * 32 + g4 * 8];
      #pragma unroll
      for (int e = 0; e < 8; ++e) bfr[kk][e] = (short)f2bf(src[e]);
    }
    f32x4 acc = {};
    #pragma unroll
    for (int kk = 0; kk < 2; ++kk)
      acc = __builtin_amdgcn_mfma_f32_16x16x32_bf16(qf[kk], bfr[kk], acc, 0, 0, 0);
    #pragma unroll
    for (int j = 0; j < 4; ++j)
      Gf[w * 1024 + (g4 * 4 + j) * 64 + nn * 16 + rr] = acc[j] * LOG2E;
  }
  __syncthreads();
  float4 bwv[4];
  #pragma unroll
  for (int j = 0; j < 4; ++j) {
    int c0 = ((q0 + w * 16 + g4 * 4 + j) & 31) + 31 - 4 * (rr & 7);
    const float* gr = &Gf[w * 1024 + (g4 * 4 + j) * 64];
    bwv[j].x = gr[c0]; bwv[j].y = gr[c0 - 1]; bwv[j].z = gr[c0 - 2]; bwv[j].w = gr[c0 - 3];
  }
  __syncthreads();   // G region about to be overwritten by KV staging

  float lsum[4] = {};
  f32x4 oacc[4] = {};

  auto stageKV = [&](int buf, int t) {
    int k0 = t * 64;
    int c = tid;                      // 512 chunks of 16B cover each 8KB tile
    int row = c >> 3, ci = c & 7;
    int swk = ci ^ ((row >> 2) & 7);
    int swv = ci ^ (row & 7);
    GLDS(Kb + (size_t)(k0 + row) * DH + swk * 8, ((u16*)Ks) + buf * 4096 + c * 8);
    GLDS(Vb + (size_t)row * SEQ + k0 + swv * 8, ((u16*)Vs) + buf * 4096 + c * 8);
  };
  stageKV(0, 0);
  stageKV(1, 1);
  asm volatile("s_waitcnt vmcnt(2)" ::: "memory");   // tile 0 (own 2 ops) complete
  __builtin_amdgcn_s_barrier();                       // -> tile 0 complete for ALL waves

  // bh for tile 0 (software-pipelined shuffle; depends only on t)
  float bhv[4];
  {
    int srcl = (l & 48) | ((rr >> 3) & 15);
    #pragma unroll
    for (int j = 0; j < 4; ++j) bhv[j] = __shfl(bh0[j], srcl);
  }

  for (int t = 0; t < 16; ++t) {
    const int cur = t % 3;
    if (t + 2 < 16) stageKV((t + 2) % 3, t + 2);

    // QK^T — kf[nn] holds K row (4*rr + nn): lane's 4 score cols are ADJACENT keys
    bf16x8 kf[4][2];
    #pragma unroll
    for (int nn = 0; nn < 4; ++nn)
      #pragma unroll
      for (int kk = 0; kk < 2; ++kk) {
        int row = 4 * rr + nn;
        int ch = (kk * 4 + g4) ^ ((row >> 2) & 7);
        kf[nn][kk] = *(const bf16x8*)(((const u16*)Ks) + cur * 4096 + row * 64 + ch * 8);
      }
    // bias pre-folded into MFMA accumulator init
    f32x4 sc[4];
    #pragma unroll
    for (int nn = 0; nn < 4; ++nn) {
      f32x4 s;
      #pragma unroll
      for (int j = 0; j < 4; ++j) s[j] = bhv[j] + ((const float*)&bwv[j])[nn];
      sc[nn] = s;
    }
    __builtin_amdgcn_s_setprio(1);
    #pragma unroll
    for (int nn = 0; nn < 4; ++nn)
      #pragma unroll
      for (int kk = 0; kk < 2; ++kk)
        sc[nn] = __builtin_amdgcn_mfma_f32_16x16x32_bf16(qf[kk], kf[nn][kk], sc[nn], 0, 0, 0);
    __builtin_amdgcn_s_setprio(0);

    // prefetch bh for tile t+1 (latency hides under softmax+PV+barrier)
    float bhvn[4];
    if (t + 1 < 16) {
      int srcl = (l & 48) | ((2 * (t + 1) + (rr >> 3)) & 15);
      #pragma unroll
      for (int j = 0; j < 4; ++j) bhvn[j] = __shfl((t + 1 < 8) ? bh0[j] : bh1[j], srcl);
    }

    // P = 2^sc; deferred row-sum; v_perm pack
    #pragma unroll
    for (int j = 0; j < 4; ++j) {
      float v0 = __builtin_amdgcn_exp2f(sc[0][j]);
      float v1 = __builtin_amdgcn_exp2f(sc[1][j]);
      float v2 = __builtin_amdgcn_exp2f(sc[2][j]);
      float v3 = __builtin_amdgcn_exp2f(sc[3][j]);
      lsum[j] += (v0 + v1) + (v2 + v3);
      uint2 pk;
      pk.x = pk_bf2(v0, v1);
      pk.y = pk_bf2(v2, v3);
      *(uint2*)&Ps[w][g4 * 4 + j][4 * rr] = pk;
    }

    // PV
    bf16x8 pa[2], vf[4][2];
    #pragma unroll
    for (int kk = 0; kk < 2; ++kk)
      pa[kk] = *(const bf16x8*)&Ps[w][rr][kk * 32 + g4 * 8];
    #pragma unroll
    for (int nn = 0; nn < 4; ++nn)
      #pragma unroll
      for (int kk = 0; kk < 2; ++kk) {
        int row = nn * 16 + rr;
        int ch = (kk * 4 + g4) ^ (row & 7);
        vf[nn][kk] = *(const bf16x8*)(((const u16*)Vs) + cur * 4096 + row * 64 + ch * 8);
      }
    __builtin_amdgcn_s_setprio(1);
    #pragma unroll
    for (int nn = 0; nn < 4; ++nn)
      #pragma unroll
      for (int kk = 0; kk < 2; ++kk)
        oacc[nn] = __builtin_amdgcn_mfma_f32_16x16x32_bf16(pa[kk], vf[nn][kk], oacc[nn], 0, 0, 0);
    __builtin_amdgcn_s_setprio(0);
    // Counted drain BEFORE the barrier: tile t+1 (issued last iter) must be staged by this
    // wave; the newest prefetch (t+2) stays in flight across the barrier.
    if (t + 2 < 16) asm volatile("s_waitcnt vmcnt(2)" ::: "memory");
    else            asm volatile("s_waitcnt vmcnt(0)" ::: "memory");
    __builtin_amdgcn_s_barrier();
    #pragma unroll
    for (int j = 0; j < 4; ++j) bhv[j] = bhvn[j];
  }

  const int b = bhi / NH, h = bhi % NH;
  #pragma unroll
  for (int j = 0; j < 4; ++j) {
    float lv = lsum[j];
    #pragma unroll
    for (int off = 1; off < 16; off <<= 1) lv += __shfl_xor(lv, off);
    float inv = 1.0f / lv;
    int p = q0 + w * 16 + g4 * 4 + j;
    #pragma unroll
    for (int nn = 0; nn < 4; ++nn) {
      int d = nn * 16 + rr;
      O[((size_t)(b * SEQ + p)) * CDIM + h * DH + d] = f2bf(oacc[nn][j] * inv);
    }
  }
}

extern "C" void kernel_launch(void* const* d_in, const int* in_sizes, int n_in,
                              void* d_out, int out_size, void* d_ws, size_t ws_size,
                              hipStream_t stream) {
  const float* x     = (const float*)d_in[0];
  const float* w_qkv = (const float*)d_in[1];
  const float* b_qkv = (const float*)d_in[2];
  const float* w_out = (const float*)d_in[3];
  const float* b_out = (const float*)d_in[4];
  const float* rph   = (const float*)d_in[5];
  const float* rpw   = (const float*)d_in[6];
  float* out = (float*)d_out;
  char* ws = (char*)d_ws;

  const size_t SZ = (size_t)BHN * SEQ * DH * 2;          // 12,582,912
  u16* Xb    = (u16*)(ws);                               // also O (attn output)
  u16* Wqkvt = (u16*)(ws + SZ);                          // 3,538,944
  u16* Woutt = (u16*)(ws + SZ + 3538944);                // 1,179,648
  u16* Qd    = (u16*)(ws + SZ + 4718592);
  u16* Kd    = (u16*)(ws + 2 * SZ + 4718592);
  u16* Vt    = (u16*)(ws + 3 * SZ + 4718592);            // V transposed, written by k_gemm
  u16* Ob    = Xb;
  if (ws_size < 4 * SZ + 4718592) return;  // scratch too small: fail visibly, no OOB

  k_prep<<<6720, 256, 0, stream>>>(x, Xb, w_qkv, Wqkvt, w_out, Woutt);
  k_gemm<18><<<1152, 512, 0, stream>>>(Xb, Wqkvt, b_qkv, Qd, Kd, Vt, 1152);
  k_attn<<<768, 512, 0, stream>>>(Qd, Kd, Vt, rph, rpw, Ob);
  k_gemmB<4><<<256, 512, 0, stream>>>(Ob, Woutt, b_out, out, 256);
}

// Round 24
// 134.428 us; speedup vs baseline: 1.0397x; 1.0397x over previous
//
#include <hip/hip_runtime.h>
#include <stdint.h>

#define NH 12
#define DH 64
#define HW_ 32
#define SEQ 1024
#define CDIM 768
#define BATCH 8
#define BHN (BATCH*NH)

#define LOG2E 1.44269504f
#define KSCALE 0.18033688f   // 0.125 * log2(e), folded into K

typedef unsigned short u16;
typedef __attribute__((ext_vector_type(4))) float f32x4;
typedef __attribute__((ext_vector_type(8))) short bf16x8;

static __device__ __forceinline__ u16 f2bf(float f) {
  union { float f; unsigned u; } v; v.f = f;
  unsigned r = v.u + 0x7fff + ((v.u >> 16) & 1);
  return (u16)(r >> 16);
}
// pack hi16(round-half-up(b)) : hi16(round-half-up(a))  (a -> low half)
static __device__ __forceinline__ unsigned pk_bf2(float a, float b) {
  union { float f; unsigned u; } ua, ub; ua.f = a; ub.f = b;
  return __builtin_amdgcn_perm(ub.u + 0x8000u, ua.u + 0x8000u, 0x07060302u);
}

#define GLDS(gp, lp) __builtin_amdgcn_global_load_lds( \
  (const __attribute__((address_space(1))) unsigned int*)(gp), \
  (__attribute__((address_space(3))) unsigned int*)(lp), 16, 0, 0)

// ---------------- fused prep: x->bf16 (blocks 0..6143), w_qkv^T (next 432), w_out^T (last 144) ----------------
__device__ __forceinline__ void transcvt_body(const float* __restrict__ w, u16* __restrict__ wt,
                                              int R, int C, int bx, int by, int tid) {
  __shared__ float t[64][65];
  const int tx = tid & 63, ty = tid >> 6;
  int c0 = bx * 64, r0 = by * 64;
  #pragma unroll
  for (int i = 0; i < 16; ++i) {
    int r = ty + i * 4;
    t[r][tx] = w[(size_t)(r0 + r) * C + c0 + tx];
  }
  __syncthreads();
  #pragma unroll
  for (int i = 0; i < 16; ++i) {
    int c = ty + i * 4;
    wt[(size_t)(c0 + c) * R + r0 + tx] = f2bf(t[tx][c]);
  }
}

__global__ void k_prep(const float* __restrict__ x, u16* __restrict__ xb,
                       const float* __restrict__ wqkv, u16* __restrict__ wqkvt,
                       const float* __restrict__ wout, u16* __restrict__ woutt) {
  const int bid = blockIdx.x, tid = threadIdx.x;
  if (bid < 6144) {
    int i = bid * 256 + tid;
    const float4 v = *(const float4*)(x + (size_t)i * 4);
    uint2 o;
    o.x = (unsigned)f2bf(v.x) | ((unsigned)f2bf(v.y) << 16);
    o.y = (unsigned)f2bf(v.z) | ((unsigned)f2bf(v.w) << 16);
    *(uint2*)(xb + (size_t)i * 4) = o;
  } else if (bid < 6144 + 432) {
    int b = bid - 6144;
    transcvt_body(wqkv, wqkvt, 768, 2304, b % 36, b / 36, tid);
  } else {
    int b = bid - 6144 - 432;
    transcvt_body(wout, woutt, 768, 768, b % 12, b / 12, tid);
  }
}

// ---------------- GEMM: A(8192,768)bf16 x Bt(N,768)bf16, 128x128 tile, 8 waves (4M x 2N) ----------------
// TRIPLE-buffered LDS, 2-tile-ahead prefetch, counted vmcnt BEFORE the raw barrier.
// 1-D grid with bijective XCD swizzle (T1).
// EPI=0: Q (bh,p,d); K scaled by KSCALE (bh,p,d); V TRANSPOSED to (bh,d,p).  EPI=1: fp32 out.
template<int EPI, int NT>
__global__ __launch_bounds__(512, 8) void k_gemm(
    const u16* __restrict__ A, const u16* __restrict__ Bt,
    const float* __restrict__ bias,
    void* __restrict__ o0, void* __restrict__ o1, void* __restrict__ o2,
    int nwg) {
  __shared__ u16 As[3][128][32];   // 24 KB
  __shared__ u16 Bs[3][128][32];   // 24 KB
  const int cpx = nwg >> 3;                       // nwg % 8 == 0
  const int swz = (blockIdx.x & 7) * cpx + (blockIdx.x >> 3);
  const int tid = threadIdx.x, w = tid >> 6, l = tid & 63;
  const int wr = w >> 1, wc = w & 1;              // wave tile 32x64
  const int rr = l & 15, g4 = l >> 4;
  const int m0 = (swz / NT) * 128, n0 = (swz % NT) * 128;
  const int K = CDIM;
  const int NT_K = K / 32;                        // 24 K-steps
  f32x4 acc[2][4] = {};

  auto stage = [&](int buf, int t) {
    int k0 = t * 32;
    int c = tid;                                   // 512 chunks of 16B each for A and B
    int row = c >> 2, kc = (c & 3) * 8;
    GLDS(A + (size_t)(m0 + row) * K + k0 + kc, ((u16*)As) + buf * 4096 + c * 8);
    GLDS(Bt + (size_t)(n0 + row) * K + k0 + kc, ((u16*)Bs) + buf * 4096 + c * 8);
  };
  stage(0, 0);
  stage(1, 1);
  asm volatile("s_waitcnt vmcnt(2)" ::: "memory");   // tile 0 (own ops) complete
  __builtin_amdgcn_s_barrier();                       // -> tile 0 complete for ALL waves
  for (int t = 0; t < NT_K; ++t) {
    const int cur = t % 3;
    if (t + 2 < NT_K) stage((t + 2) % 3, t + 2);
    bf16x8 af[2], bfr[4];
    #pragma unroll
    for (int mm = 0; mm < 2; ++mm)
      af[mm] = *(const bf16x8*)(((const u16*)As) + cur * 4096 + (wr * 32 + mm * 16 + rr) * 32 + g4 * 8);
    #pragma unroll
    for (int nn = 0; nn < 4; ++nn)
      bfr[nn] = *(const bf16x8*)(((const u16*)Bs) + cur * 4096 + (wc * 64 + nn * 16 + rr) * 32 + g4 * 8);
    __builtin_amdgcn_s_setprio(1);
    #pragma unroll
    for (int mm = 0; mm < 2; ++mm)
      #pragma unroll
      for (int nn = 0; nn < 4; ++nn)
        acc[mm][nn] = __builtin_amdgcn_mfma_f32_16x16x32_bf16(af[mm], bfr[nn], acc[mm][nn], 0, 0, 0);
    __builtin_amdgcn_s_setprio(0);
    if (t + 2 < NT_K) asm volatile("s_waitcnt vmcnt(2)" ::: "memory");
    else              asm volatile("s_waitcnt vmcnt(0)" ::: "memory");
    __builtin_amdgcn_s_barrier();
  }
  #pragma unroll
  for (int mm = 0; mm < 2; ++mm)
    #pragma unroll
    for (int nn = 0; nn < 4; ++nn) {
      int row0 = m0 + wr * 32 + mm * 16 + g4 * 4;
      int col = n0 + wc * 64 + nn * 16 + rr;
      float bb = bias[col];
      if (EPI == 0) {
        int which = col / CDIM, rem = col % CDIM;
        int hh = rem >> 6, d = rem & 63;
        int b = row0 >> 10, p = row0 & 1023;
        if (which == 2) {
          uint2 pk;
          pk.x = (unsigned)f2bf(acc[mm][nn][0] + bb) | ((unsigned)f2bf(acc[mm][nn][1] + bb) << 16);
          pk.y = (unsigned)f2bf(acc[mm][nn][2] + bb) | ((unsigned)f2bf(acc[mm][nn][3] + bb) << 16);
          *(uint2*)&((u16*)o2)[((size_t)(b * NH + hh) * DH + d) * SEQ + p] = pk;
        } else if (which == 1) {
          #pragma unroll
          for (int j = 0; j < 4; ++j)
            ((u16*)o1)[(((size_t)(b * NH + hh)) * SEQ + p + j) * DH + d] = f2bf((acc[mm][nn][j] + bb) * KSCALE);
        } else {
          #pragma unroll
          for (int j = 0; j < 4; ++j)
            ((u16*)o0)[(((size_t)(b * NH + hh)) * SEQ + p + j) * DH + d] = f2bf(acc[mm][nn][j] + bb);
        }
      } else {
        #pragma unroll
        for (int j = 0; j < 4; ++j)
          ((float*)o0)[(size_t)(row0 + j) * CDIM + col] = acc[mm][nn][j] + bb;
      }
    }
}

// ---------------- flash attention with IN-BLOCK rel-pos bias (relbias fused) ----------------
// 8 waves x 16 q-rows; K pre-scaled by 0.125*log2e; bias computed here, pre-scaled by log2e.
// Bias pre-folded into QK MFMA C-init; bh shuffle software-pipelined one tile ahead.
// TRIPLE-buffered K/V (depth-2 prefetch) + counted vmcnt BEFORE raw barrier (R19 pattern).
// P = 2^(sc) via v_exp_f32. No-max softmax (scores bounded). XCD-local K/V.
__global__ __launch_bounds__(512, 4) void k_attn(
    const u16* __restrict__ Q, const u16* __restrict__ Kg,
    const u16* __restrict__ Vtg,
    const float* __restrict__ rph, const float* __restrict__ rpw,
    u16* __restrict__ O) {
  __shared__ u16 Ks[3][64][64];   // 24 KB; [key][d]; swizzle mask (row>>2)&7
  __shared__ u16 Vs[3][64][64];   // 24 KB; [d][key]; swizzle mask row&7
  __shared__ u16 Ps[8][16][72];   // per-wave P tile [query][key]
  const int bid = blockIdx.x;
  const int bhi = bid % 96;            // 96%8==0 -> all q-blocks of a bh on one XCD
  const int q0 = (bid / 96) * 128;
  const int tid = threadIdx.x, w = tid >> 6, l = tid & 63;
  const int rr = l & 15, g4 = l >> 4;
  const u16* Qb = Q + (size_t)bhi * SEQ * DH;
  const u16* Kb = Kg + (size_t)bhi * SEQ * DH;
  const u16* Vb = Vtg + (size_t)bhi * SEQ * DH;   // (64,1024)

  // Q fragment: wave's 16 rows (q0 + w*16 + rr)
  bf16x8 qf[2];
  #pragma unroll
  for (int kk = 0; kk < 2; ++kk)
    qf[kk] = *(const bf16x8*)&Qb[(size_t)(q0 + w * 16 + rr) * DH + kk * 32 + g4 * 8];

  // ---- in-block bias: bH (4 MFMAs, lands directly in bh0/bh1 layout) ----
  const int hq = (q0 >> 5) + (w >> 1);
  float bh0[4], bh1[4];
  {
    f32x4 accH[2] = {{}, {}};
    #pragma unroll
    for (int nn = 0; nn < 2; ++nn) {
      bf16x8 bfr[2];
      #pragma unroll
      for (int kk = 0; kk < 2; ++kk) {
        const float* src = &rph[(size_t)(hq - (nn * 16 + rr) + 31) * DH + kk * 32 + g4 * 8];
        #pragma unroll
        for (int e = 0; e < 8; ++e) bfr[kk][e] = (short)f2bf(src[e]);
      }
      #pragma unroll
      for (int kk = 0; kk < 2; ++kk)
        accH[nn] = __builtin_amdgcn_mfma_f32_16x16x32_bf16(qf[kk], bfr[kk], accH[nn], 0, 0, 0);
    }
    #pragma unroll
    for (int j = 0; j < 4; ++j) { bh0[j] = accH[0][j] * LOG2E; bh1[j] = accH[1][j] * LOG2E; }
  }

  // ---- in-block bias: G = Q . rpw^T (16x64 per wave) into Ks/Vs LDS area, then gather bW ----
  float* Gf = (float*)&Ks[0][0][0];   // 8 waves x 16 x 64 floats = 32 KB (fits in Ks+Vs region)
  #pragma unroll
  for (int nn = 0; nn < 4; ++nn) {
    int j_ = nn * 16 + rr; if (j_ > 62) j_ = 62;
    bf16x8 bfr[2];
    #pragma unroll
    for (int kk = 0; kk < 2; ++kk) {
      const float* src = &rpw[(size_t)j_ * DH + kk * 32 + g4 * 8];
      #pragma unroll
      for (int e = 0; e < 8; ++e) bfr[kk][e] = (short)f2bf(src[e]);
    }
    f32x4 acc = {};
    #pragma unroll
    for (int kk = 0; kk < 2; ++kk)
      acc = __builtin_amdgcn_mfma_f32_16x16x32_bf16(qf[kk], bfr[kk], acc, 0, 0, 0);
    #pragma unroll
    for (int j = 0; j < 4; ++j)
      Gf[w * 1024 + (g4 * 4 + j) * 64 + nn * 16 + rr] = acc[j] * LOG2E;
  }
  __syncthreads();
  float4 bwv[4];
  #pragma unroll
  for (int j = 0; j < 4; ++j) {
    int c0 = ((q0 + w * 16 + g4 * 4 + j) & 31) + 31 - 4 * (rr & 7);
    const float* gr = &Gf[w * 1024 + (g4 * 4 + j) * 64];
    bwv[j].x = gr[c0]; bwv[j].y = gr[c0 - 1]; bwv[j].z = gr[c0 - 2]; bwv[j].w = gr[c0 - 3];
  }
  __syncthreads();   // G region about to be overwritten by KV staging

  float lsum[4] = {};
  f32x4 oacc[4] = {};

  auto stageKV = [&](int buf, int t) {
    int k0 = t * 64;
    int c = tid;                      // 512 chunks of 16B cover each 8KB tile
    int row = c >> 3, ci = c & 7;
    int swk = ci ^ ((row >> 2) & 7);
    int swv = ci ^ (row & 7);
    GLDS(Kb + (size_t)(k0 + row) * DH + swk * 8, ((u16*)Ks) + buf * 4096 + c * 8);
    GLDS(Vb + (size_t)row * SEQ + k0 + swv * 8, ((u16*)Vs) + buf * 4096 + c * 8);
  };
  stageKV(0, 0);
  stageKV(1, 1);
  asm volatile("s_waitcnt vmcnt(2)" ::: "memory");   // tile 0 (own 2 ops) complete
  __builtin_amdgcn_s_barrier();                       // -> tile 0 complete for ALL waves

  // bh for tile 0 (software-pipelined shuffle; depends only on t)
  float bhv[4];
  {
    int srcl = (l & 48) | ((rr >> 3) & 15);
    #pragma unroll
    for (int j = 0; j < 4; ++j) bhv[j] = __shfl(bh0[j], srcl);
  }

  for (int t = 0; t < 16; ++t) {
    const int cur = t % 3;
    if (t + 2 < 16) stageKV((t + 2) % 3, t + 2);

    // QK^T — kf[nn] holds K row (4*rr + nn): lane's 4 score cols are ADJACENT keys
    bf16x8 kf[4][2];
    #pragma unroll
    for (int nn = 0; nn < 4; ++nn)
      #pragma unroll
      for (int kk = 0; kk < 2; ++kk) {
        int row = 4 * rr + nn;
        int ch = (kk * 4 + g4) ^ ((row >> 2) & 7);
        kf[nn][kk] = *(const bf16x8*)(((const u16*)Ks) + cur * 4096 + row * 64 + ch * 8);
      }
    // bias pre-folded into MFMA accumulator init
    f32x4 sc[4];
    #pragma unroll
    for (int nn = 0; nn < 4; ++nn) {
      f32x4 s;
      #pragma unroll
      for (int j = 0; j < 4; ++j) s[j] = bhv[j] + ((const float*)&bwv[j])[nn];
      sc[nn] = s;
    }
    __builtin_amdgcn_s_setprio(1);
    #pragma unroll
    for (int nn = 0; nn < 4; ++nn)
      #pragma unroll
      for (int kk = 0; kk < 2; ++kk)
        sc[nn] = __builtin_amdgcn_mfma_f32_16x16x32_bf16(qf[kk], kf[nn][kk], sc[nn], 0, 0, 0);
    __builtin_amdgcn_s_setprio(0);

    // prefetch bh for tile t+1 (latency hides under softmax+PV+barrier)
    float bhvn[4];
    if (t + 1 < 16) {
      int srcl = (l & 48) | ((2 * (t + 1) + (rr >> 3)) & 15);
      #pragma unroll
      for (int j = 0; j < 4; ++j) bhvn[j] = __shfl((t + 1 < 8) ? bh0[j] : bh1[j], srcl);
    }

    // P = 2^sc; deferred row-sum; v_perm pack
    #pragma unroll
    for (int j = 0; j < 4; ++j) {
      float v0 = __builtin_amdgcn_exp2f(sc[0][j]);
      float v1 = __builtin_amdgcn_exp2f(sc[1][j]);
      float v2 = __builtin_amdgcn_exp2f(sc[2][j]);
      float v3 = __builtin_amdgcn_exp2f(sc[3][j]);
      lsum[j] += (v0 + v1) + (v2 + v3);
      uint2 pk;
      pk.x = pk_bf2(v0, v1);
      pk.y = pk_bf2(v2, v3);
      *(uint2*)&Ps[w][g4 * 4 + j][4 * rr] = pk;
    }

    // PV
    bf16x8 pa[2], vf[4][2];
    #pragma unroll
    for (int kk = 0; kk < 2; ++kk)
      pa[kk] = *(const bf16x8*)&Ps[w][rr][kk * 32 + g4 * 8];
    #pragma unroll
    for (int nn = 0; nn < 4; ++nn)
      #pragma unroll
      for (int kk = 0; kk < 2; ++kk) {
        int row = nn * 16 + rr;
        int ch = (kk * 4 + g4) ^ (row & 7);
        vf[nn][kk] = *(const bf16x8*)(((const u16*)Vs) + cur * 4096 + row * 64 + ch * 8);
      }
    __builtin_amdgcn_s_setprio(1);
    #pragma unroll
    for (int nn = 0; nn < 4; ++nn)
      #pragma unroll
      for (int kk = 0; kk < 2; ++kk)
        oacc[nn] = __builtin_amdgcn_mfma_f32_16x16x32_bf16(pa[kk], vf[nn][kk], oacc[nn], 0, 0, 0);
    __builtin_amdgcn_s_setprio(0);
    // Counted drain BEFORE the barrier: tile t+1 (issued last iter) must be staged by this
    // wave; the newest prefetch (t+2) stays in flight across the barrier.
    if (t + 2 < 16) asm volatile("s_waitcnt vmcnt(2)" ::: "memory");
    else            asm volatile("s_waitcnt vmcnt(0)" ::: "memory");
    __builtin_amdgcn_s_barrier();
    #pragma unroll
    for (int j = 0; j < 4; ++j) bhv[j] = bhvn[j];
  }

  const int b = bhi / NH, h = bhi % NH;
  #pragma unroll
  for (int j = 0; j < 4; ++j) {
    float lv = lsum[j];
    #pragma unroll
    for (int off = 1; off < 16; off <<= 1) lv += __shfl_xor(lv, off);
    float inv = 1.0f / lv;
    int p = q0 + w * 16 + g4 * 4 + j;
    #pragma unroll
    for (int nn = 0; nn < 4; ++nn) {
      int d = nn * 16 + rr;
      O[((size_t)(b * SEQ + p)) * CDIM + h * DH + d] = f2bf(oacc[nn][j] * inv);
    }
  }
}

extern "C" void kernel_launch(void* const* d_in, const int* in_sizes, int n_in,
                              void* d_out, int out_size, void* d_ws, size_t ws_size,
                              hipStream_t stream) {
  const float* x     = (const float*)d_in[0];
  const float* w_qkv = (const float*)d_in[1];
  const float* b_qkv = (const float*)d_in[2];
  const float* w_out = (const float*)d_in[3];
  const float* b_out = (const float*)d_in[4];
  const float* rph   = (const float*)d_in[5];
  const float* rpw   = (const float*)d_in[6];
  float* out = (float*)d_out;
  char* ws = (char*)d_ws;

  const size_t SZ = (size_t)BHN * SEQ * DH * 2;          // 12,582,912
  u16* Xb    = (u16*)(ws);                               // also O (attn output)
  u16* Wqkvt = (u16*)(ws + SZ);                          // 3,538,944
  u16* Woutt = (u16*)(ws + SZ + 3538944);                // 1,179,648
  u16* Qd    = (u16*)(ws + SZ + 4718592);
  u16* Kd    = (u16*)(ws + 2 * SZ + 4718592);
  u16* Vt    = (u16*)(ws + 3 * SZ + 4718592);            // V transposed, written by k_gemm<0>
  u16* Ob    = Xb;
  if (ws_size < 4 * SZ + 4718592) return;  // scratch too small: fail visibly, no OOB

  k_prep<<<6720, 256, 0, stream>>>(x, Xb, w_qkv, Wqkvt, w_out, Woutt);
  k_gemm<0, 18><<<1152, 512, 0, stream>>>(Xb, Wqkvt, b_qkv, Qd, Kd, Vt, 1152);
  k_attn<<<768, 512, 0, stream>>>(Qd, Kd, Vt, rph, rpw, Ob);
  k_gemm<1, 6><<<384, 512, 0, stream>>>(Ob, Woutt, b_out, out, nullptr, nullptr, 384);
}